// Round 10
// baseline (1000.686 us; speedup 1.0000x reference)
//
#include <hip/hip_runtime.h>
#include <hip/hip_bf16.h>
#include <stdint.h>

typedef __attribute__((ext_vector_type(8))) short short8;
typedef __attribute__((ext_vector_type(8))) unsigned short ushort8;
typedef __attribute__((ext_vector_type(4))) float f32x4;

#define K_DIM 4096
#define N_DIM 11008
#define M_DIM 8192
#define BM 256
#define BN 128
#define BK 32
#define TILES (K_DIM / BK)   // 128

__constant__ float c_nf4[16] = {
    -1.0f, -0.6961928009986877f, -0.5250730514526367f, -0.39491748809814453f,
    -0.28444138169288635f, -0.18477343022823334f, -0.09105003625154495f, 0.0f,
    0.07958029955625534f, 0.16093020141124725f, 0.24611230194568634f,
    0.33791524171829224f, 0.44070982933044434f, 0.5626170039176941f,
    0.7229568362236023f, 1.0f};

__device__ __forceinline__ unsigned short f2bf(float f) {
    uint32_t u = __float_as_uint(f);
    u += 0x7fffu + ((u >> 16) & 1u);   // round-to-nearest-even (finite inputs)
    return (unsigned short)(u >> 16);
}

__global__ __launch_bounds__(256) void nf4_dequant_w(const int* __restrict__ q,
                                                     const float* __restrict__ absmax,
                                                     unsigned short* __restrict__ w) {
    __shared__ float lut[16];
    if (threadIdx.x < 16) lut[threadIdx.x] = c_nf4[threadIdx.x];
    __syncthreads();
    size_t t = (size_t)blockIdx.x * 256 + threadIdx.x;
    const int4* q4 = (const int4*)q;
    int4 qa = q4[2 * t];
    int4 qb = q4[2 * t + 1];
    float s = absmax[t >> 3];
    ushort8 o;
    o[0] = f2bf(lut[qa.x & 15] * s);
    o[1] = f2bf(lut[qa.y & 15] * s);
    o[2] = f2bf(lut[qa.z & 15] * s);
    o[3] = f2bf(lut[qa.w & 15] * s);
    o[4] = f2bf(lut[qb.x & 15] * s);
    o[5] = f2bf(lut[qb.y & 15] * s);
    o[6] = f2bf(lut[qb.z & 15] * s);
    o[7] = f2bf(lut[qb.w & 15] * s);
    ((ushort8*)w)[t] = o;
}

__global__ __launch_bounds__(256) void x_to_bf16(const float* __restrict__ x,
                                                 unsigned short* __restrict__ xb) {
    size_t t = (size_t)blockIdx.x * 256 + threadIdx.x;
    const float4* x4 = (const float4*)x;
    float4 a = x4[2 * t];
    float4 b = x4[2 * t + 1];
    ushort8 o;
    o[0] = f2bf(a.x); o[1] = f2bf(a.y); o[2] = f2bf(a.z); o[3] = f2bf(a.w);
    o[4] = f2bf(b.x); o[5] = f2bf(b.y); o[6] = f2bf(b.z); o[7] = f2bf(b.w);
    ((ushort8*)xb)[t] = o;
}

// Stage a [ROWS][32] bf16 sub-tile (linear LDS, HW: uniform base + lane*16B).
// NG = gloads/thread: A (256 rows) NG=4, B (128 rows) NG=2. 256 threads.
#define STAGE(gbase, lds_sub, NG, k0)                                         \
  do {                                                                        \
    _Pragma("unroll")                                                         \
    for (int _g = 0; _g < NG; ++_g) {                                         \
      const int _i = _g * 256 + tid;       /* chunk index */                  \
      const int _r = _i >> 2;              /* row */                          \
      const int _c = (_i & 3) << 3;        /* col elem 0,8,16,24 */           \
      __builtin_amdgcn_global_load_lds(                                       \
          (const __attribute__((address_space(1))) void*)((gbase) +           \
              (size_t)_r * K_DIM + (k0) + _c),                                \
          (__attribute__((address_space(3))) void*)((lds_sub) +               \
              (_g * 256 + wave * 64) * 8),                                    \
          16, 0, 0);                                                          \
    }                                                                         \
  } while (0)

#define MFMA32                                                                \
  do {                                                                        \
    _Pragma("unroll")                                                         \
    for (int _m = 0; _m < 8; ++_m) {                                          \
      _Pragma("unroll")                                                       \
      for (int _n = 0; _n < 4; ++_n)                                          \
        acc[_m][_n] = __builtin_amdgcn_mfma_f32_16x16x32_bf16(                \
            af[_m], bfr[_n], acc[_m][_n], 0, 0, 0);                           \
    }                                                                         \
  } while (0)

// 256x128 tile, BK=32, 4 waves (2M x 2N, 128x64 each), dbuf-2 (48 KB LDS ->
// TWO blocks/CU). Loose schedule (1 barrier/tile). Cross-block phase drift
// (m97/m114 mechanism) overlaps one block's DS burst with the other's MFMA.
__global__ __launch_bounds__(256, 2) void gemm256(const unsigned short* __restrict__ A,
                                                  const unsigned short* __restrict__ B,
                                                  const float* __restrict__ bias,
                                                  float* __restrict__ C) {
    __shared__ unsigned short As[2][BM * 32];   // 2 x 16 KB
    __shared__ unsigned short Bs[2][BN * 32];   // 2 x  8 KB -> 48 KB total

    const int tid  = threadIdx.x;
    const int wave = tid >> 6;
    const int lane = tid & 63;
    const int wm = wave >> 1;               // 0..1 -> A 128-row slab
    const int wn = wave & 1;                // 0..1 -> B 64-row slab
    const int lr = lane & 15;
    const int q8 = (lane >> 4) << 3;        // k elem offset (0,8,16,24)

    // XCD-aware bijective swizzle: grid = 2752, 2752 % 8 == 0.
    const int nbn = N_DIM / BN;             // 86
    const int cpx = (int)gridDim.x >> 3;    // 344
    const int bid = (int)blockIdx.x;
    const int swz = (bid & 7) * cpx + (bid >> 3);
    const int bm = swz / nbn;
    const int bn = swz % nbn;

    const unsigned short* Ab = A + (size_t)bm * BM * K_DIM;
    const unsigned short* Bb = B + (size_t)bn * BN * K_DIM;

    f32x4 acc[8][4];
#pragma unroll
    for (int i = 0; i < 8; ++i)
#pragma unroll
        for (int j = 0; j < 4; ++j)
#pragma unroll
            for (int v = 0; v < 4; ++v) acc[i][j][v] = 0.0f;

    // Prologue: stage tile 0; drain; barrier.
    STAGE(Ab, &As[0][0], 4, 0);
    STAGE(Bb, &Bs[0][0], 2, 0);
    asm volatile("s_waitcnt vmcnt(0)" ::: "memory");
    asm volatile("s_barrier" ::: "memory");

    short8 af[8], bfr[4];

#pragma unroll 1
    for (int t = 0; t < TILES; ++t) {
        const int p = t & 1;
        int t1 = t + 1; if (t1 >= TILES) t1 = 0;   // tail wrap: harmless
        const int k1 = t1 * BK;
        const unsigned short* Ah = &As[p][0];
        const unsigned short* Bh = &Bs[p][0];

        // Issue next-tile stages first: in-flight window = the whole tile.
        STAGE(Ab, &As[p ^ 1][0], 4, k1);
        STAGE(Bb, &Bs[p ^ 1][0], 2, k1);

        // Frag reads (12 x ds_read_b128) into named reg sets.
#pragma unroll
        for (int mi = 0; mi < 8; ++mi)
            af[mi] = *(const short8*)(Ah + (wm * 128 + mi * 16 + lr) * 32 + q8);
#pragma unroll
        for (int ni = 0; ni < 4; ++ni)
            bfr[ni] = *(const short8*)(Bh + (wn * 64 + ni * 16 + lr) * 32 + q8);

        __builtin_amdgcn_s_setprio(1);
        MFMA32;
        __builtin_amdgcn_s_setprio(0);

        // Tile boundary: reads complete before others overwrite buf p (WAR),
        // next tile's data landed (RAW), one barrier.
        asm volatile("s_waitcnt lgkmcnt(0)" ::: "memory");
        __builtin_amdgcn_sched_barrier(0);
        asm volatile("s_waitcnt vmcnt(0)" ::: "memory");
        asm volatile("s_barrier" ::: "memory");
    }
    asm volatile("s_waitcnt vmcnt(0)" ::: "memory");

    // Epilogue: C/D layout col = lane&15, row = (lane>>4)*4 + v (m89/m91).
    const int row0 = bm * BM + wm * 128 + ((lane >> 4) << 2);
    const int col0 = bn * BN + wn * 64 + lr;
#pragma unroll
    for (int ni = 0; ni < 4; ++ni) {
        const int col = col0 + ni * 16;
        const float bv = bias[col];
#pragma unroll
        for (int mi = 0; mi < 8; ++mi) {
#pragma unroll
            for (int v = 0; v < 4; ++v) {
                C[(size_t)(row0 + mi * 16 + v) * N_DIM + col] = acc[mi][ni][v] + bv;
            }
        }
    }
}

extern "C" void kernel_launch(void* const* d_in, const int* in_sizes, int n_in,
                              void* d_out, int out_size, void* d_ws, size_t ws_size,
                              hipStream_t stream) {
    const float* x    = (const float*)d_in[0];   // [4,2048,4096] f32
    const int*   wq   = (const int*)d_in[1];     // [11008,4096] int32 in 0..15
    const float* am   = (const float*)d_in[2];   // [11008,64] f32
    const float* bias = (const float*)d_in[3];   // [11008] f32
    float* out = (float*)d_out;                  // [4,2048,11008] f32

    const size_t w_elems = (size_t)N_DIM * K_DIM;
    const size_t x_elems = (size_t)M_DIM * K_DIM;
    const size_t need = (w_elems + x_elems) * sizeof(unsigned short);
    if (ws_size < need) return;

    unsigned short* wbf = (unsigned short*)d_ws;
    unsigned short* xbf = wbf + w_elems;

    nf4_dequant_w<<<(int)(w_elems / 8 / 256), 256, 0, stream>>>(wq, am, wbf);
    x_to_bf16<<<(int)(x_elems / 8 / 256), 256, 0, stream>>>(x, xbf);

    const int grid = (M_DIM / BM) * (N_DIM / BN);   // 32 * 86 = 2752
    gemm256<<<grid, 256, 0, stream>>>(xbf, wbf, bias, out);
}

// Round 11
// 861.800 us; speedup vs baseline: 1.1612x; 1.1612x over previous
//
#include <hip/hip_runtime.h>
#include <hip/hip_bf16.h>
#include <stdint.h>

typedef __attribute__((ext_vector_type(8))) short short8;
typedef __attribute__((ext_vector_type(8))) unsigned short ushort8;
typedef __attribute__((ext_vector_type(4))) float f32x4;

#define K_DIM 4096
#define N_DIM 11008
#define M_DIM 8192
#define BM 256
#define BN 256
#define BK 64
#define TILES (K_DIM / BK)   // 64
#define ITERS (TILES / 2)    // 32

__constant__ float c_nf4[16] = {
    -1.0f, -0.6961928009986877f, -0.5250730514526367f, -0.39491748809814453f,
    -0.28444138169288635f, -0.18477343022823334f, -0.09105003625154495f, 0.0f,
    0.07958029955625534f, 0.16093020141124725f, 0.24611230194568634f,
    0.33791524171829224f, 0.44070982933044434f, 0.5626170039176941f,
    0.7229568362236023f, 1.0f};

__device__ __forceinline__ unsigned short f2bf(float f) {
    uint32_t u = __float_as_uint(f);
    u += 0x7fffu + ((u >> 16) & 1u);   // round-to-nearest-even (finite inputs)
    return (unsigned short)(u >> 16);
}

__global__ __launch_bounds__(256) void nf4_dequant_w(const int* __restrict__ q,
                                                     const float* __restrict__ absmax,
                                                     unsigned short* __restrict__ w) {
    __shared__ float lut[16];
    if (threadIdx.x < 16) lut[threadIdx.x] = c_nf4[threadIdx.x];
    __syncthreads();
    size_t t = (size_t)blockIdx.x * 256 + threadIdx.x;
    const int4* q4 = (const int4*)q;
    int4 qa = q4[2 * t];
    int4 qb = q4[2 * t + 1];
    float s = absmax[t >> 3];
    ushort8 o;
    o[0] = f2bf(lut[qa.x & 15] * s);
    o[1] = f2bf(lut[qa.y & 15] * s);
    o[2] = f2bf(lut[qa.z & 15] * s);
    o[3] = f2bf(lut[qa.w & 15] * s);
    o[4] = f2bf(lut[qb.x & 15] * s);
    o[5] = f2bf(lut[qb.y & 15] * s);
    o[6] = f2bf(lut[qb.z & 15] * s);
    o[7] = f2bf(lut[qb.w & 15] * s);
    ((ushort8*)w)[t] = o;
}

__global__ __launch_bounds__(256) void x_to_bf16(const float* __restrict__ x,
                                                 unsigned short* __restrict__ xb) {
    size_t t = (size_t)blockIdx.x * 256 + threadIdx.x;
    const float4* x4 = (const float4*)x;
    float4 a = x4[2 * t];
    float4 b = x4[2 * t + 1];
    ushort8 o;
    o[0] = f2bf(a.x); o[1] = f2bf(a.y); o[2] = f2bf(a.z); o[3] = f2bf(a.w);
    o[4] = f2bf(b.x); o[5] = f2bf(b.y); o[6] = f2bf(b.z); o[7] = f2bf(b.w);
    ((ushort8*)xb)[t] = o;
}

// Stage one 128-row half [128][64] (16 KB): 2 gloads/thread, LDS dest linear,
// GLOBAL source chunk G4-swizzled (r4/r6/r7-proven zero-conflict):
// LDS slot (r, s) holds global chunk s ^ (r&7).
#define STAGE_HALF(gbase, lds_half, row0, k0)                                 \
  do {                                                                        \
    _Pragma("unroll")                                                         \
    for (int _g = 0; _g < 2; ++_g) {                                          \
      const int _i = _g * 512 + tid;                                          \
      const int _r = _i >> 3;                                                 \
      const int _c = (_i & 7) ^ (_r & 7);                                     \
      __builtin_amdgcn_global_load_lds(                                       \
          (const __attribute__((address_space(1))) void*)((gbase) +           \
              (size_t)((row0) + _r) * K_DIM + (k0) + _c * 8),                 \
          (__attribute__((address_space(3))) void*)((lds_half) +              \
              (_g * 512 + wave * 64) * 8),                                    \
          16, 0, 0);                                                          \
    }                                                                         \
  } while (0)

// Quadrant reads (full K=64): A: 4 frag-rows x 2 kk = 8 b128; B: 2 x 2 = 4.
#define DS_A8(dst, Ah, qr)                                                    \
  do {                                                                        \
    _Pragma("unroll")                                                         \
    for (int _m = 0; _m < 4; ++_m) {                                          \
      dst[_m][0] = *(const short8*)((Ah) + ((qr) + _m * 16) * 64 + roff);     \
      dst[_m][1] = *(const short8*)((Ah) + ((qr) + _m * 16) * 64 + (roff ^ 32)); \
    }                                                                         \
  } while (0)

#define DS_B4(dst, Bh, qc)                                                    \
  do {                                                                        \
    _Pragma("unroll")                                                         \
    for (int _n = 0; _n < 2; ++_n) {                                          \
      dst[_n][0] = *(const short8*)((Bh) + (lb + (qc) + _n * 16) * 64 + roff); \
      dst[_n][1] = *(const short8*)((Bh) + (lb + (qc) + _n * 16) * 64 + (roff ^ 32)); \
    }                                                                         \
  } while (0)

// One C-quadrant x K=64: 16 MFMA, k outermost (no acc back-to-back deps).
#define MFMAQ(MI0, NI0, Ar, Br)                                               \
  do {                                                                        \
    _Pragma("unroll")                                                         \
    for (int _k = 0; _k < 2; ++_k) {                                          \
      _Pragma("unroll")                                                       \
      for (int _m = 0; _m < 4; ++_m) {                                        \
        _Pragma("unroll")                                                     \
        for (int _n = 0; _n < 2; ++_n)                                        \
          acc[(MI0) + _m][(NI0) + _n] = __builtin_amdgcn_mfma_f32_16x16x32_bf16( \
              Ar[_m][_k], Br[_n][_k], acc[(MI0) + _m][(NI0) + _n], 0, 0, 0);  \
      }                                                                       \
    }                                                                         \
  } while (0)

#define BAR   asm volatile("s_barrier" ::: "memory")
#define SB0   __builtin_amdgcn_sched_barrier(0)
#define LGKM0 do { asm volatile("s_waitcnt lgkmcnt(0)" ::: "memory"); SB0; } while (0)

#define PH_COMPUTE(MI0, NI0, Ar, Br)                                          \
  BAR; LGKM0;                                                                 \
  __builtin_amdgcn_s_setprio(1);                                              \
  MFMAQ(MI0, NI0, Ar, Br);                                                    \
  __builtin_amdgcn_s_setprio(0);                                              \
  SB0;

// Faithful m201 8-phase schedule: 256x256, BK=64, 8 waves (2M x 4N), dbuf-2
// row-half LDS + G4 swizzle, 2 K-tiles/iteration, quadrant-K64 phases,
// per-phase half staging, vmcnt(4)@Ph4 / vmcnt(6)@Ph8 (never 0 in loop).
__global__ __launch_bounds__(512, 2) void gemm256(const unsigned short* __restrict__ A,
                                                  const unsigned short* __restrict__ B,
                                                  const float* __restrict__ bias,
                                                  float* __restrict__ C) {
    __shared__ unsigned short As[2][2][128 * 64];   // [buf][row-half], 64 KB
    __shared__ unsigned short Bs[2][2][128 * 64];   // 64 KB -> 128 KB total

    const int tid  = threadIdx.x;
    const int wave = tid >> 6;
    const int lane = tid & 63;
    const int wm = wave >> 2;               // 0..1 -> A row-half
    const int wn = wave & 3;                // 0..3 -> 64-col B slab
    const int lr = lane & 15;
    const int q  = lane >> 4;               // 0..3
    const int roff = lr * 64 + ((q ^ (lr & 7)) << 3);  // swizzled, kk=0
    const int lb = (wn & 1) * 64;           // B row base within its half

    // XCD-aware bijective swizzle: grid = 1376, 1376 % 8 == 0.
    const int nbn = N_DIM / BN;             // 43
    const int cpx = (int)gridDim.x >> 3;    // 172
    const int bid = (int)blockIdx.x;
    const int swz = (bid & 7) * cpx + (bid >> 3);
    const int bm = swz / nbn;
    const int bn = swz % nbn;

    const unsigned short* Ab = A + (size_t)bm * BM * K_DIM;
    const unsigned short* Bb = B + (size_t)bn * BN * K_DIM;

    f32x4 acc[8][4];
#pragma unroll
    for (int i = 0; i < 8; ++i)
#pragma unroll
        for (int j = 0; j < 4; ++j)
#pragma unroll
            for (int v = 0; v < 4; ++v) acc[i][j][v] = 0.0f;

    // Prologue: 7 halves in steady-state queue order; vmcnt(6) retires tile 0.
    STAGE_HALF(Bb, &Bs[0][0][0], 0,   0);    // B0h0
    STAGE_HALF(Bb, &Bs[0][1][0], 128, 0);    // B0h1
    STAGE_HALF(Ab, &As[0][0][0], 0,   0);    // A0h0
    STAGE_HALF(Ab, &As[0][1][0], 128, 0);    // A0h1
    STAGE_HALF(Bb, &Bs[1][0][0], 0,   BK);   // B1h0
    STAGE_HALF(Bb, &Bs[1][1][0], 128, BK);   // B1h1
    STAGE_HALF(Ab, &As[1][0][0], 0,   BK);   // A1h0
    asm volatile("s_waitcnt vmcnt(6)" ::: "memory");
    BAR;

    short8 aS[4][2], aT[4][2], b0[2][2], b1[2][2];

#pragma unroll 1
    for (int i = 0; i < ITERS; ++i) {
        const int u  = 2 * i;
        const int v  = (u + 1) & (TILES - 1);
        const int t2 = (u + 2) & (TILES - 1);   // tail wrap: harmless re-stage
        const int t3 = (u + 3) & (TILES - 1);
        const unsigned short* A0 = &As[0][wm][0];
        const unsigned short* B0h = &Bs[0][wn >> 1][0];
        const unsigned short* A1 = &As[1][wm][0];
        const unsigned short* B1h = &Bs[1][wn >> 1][0];

        // ---- Ph1: tile u, quad(rows 0-63, cols 0-31); stage A(v)h1 ----
        DS_A8(aS, A0, 0);
        DS_B4(b0, B0h, 0);
        STAGE_HALF(Ab, &As[1][1][0], 128, v * BK);
        PH_COMPUTE(0, 0, aS, b0);
        BAR;

        // ---- Ph2: quad(0-63, 32-63); no stage ----
        DS_B4(b1, B0h, 32);
        PH_COMPUTE(0, 2, aS, b1);
        BAR;

        // ---- Ph3: quad(64-127, 0-31); stage B(t2)h0 (Bs[0][*] free) ----
        DS_A8(aT, A0, 64);
        STAGE_HALF(Bb, &Bs[0][0][0], 0, t2 * BK);
        PH_COMPUTE(4, 0, aT, b0);
        BAR;

        // ---- Ph4: quad(64-127, 32-63); stage B(t2)h1; vmcnt(4) ----
        STAGE_HALF(Bb, &Bs[0][1][0], 128, t2 * BK);
        BAR; SB0;
        __builtin_amdgcn_s_setprio(1);
        MFMAQ(4, 2, aT, b1);
        __builtin_amdgcn_s_setprio(0);
        SB0;
        // Retires tile v's 4 halves (prevPh7,8a,8b,Ph1); leaves B(t2) in flight.
        asm volatile("s_waitcnt vmcnt(4)" ::: "memory");
        BAR;

        // ---- Ph5: tile v, quad(0-63, 0-31); stage A(t2)h0 (As[0][*] free) ----
        DS_A8(aS, A1, 0);
        DS_B4(b0, B1h, 0);
        STAGE_HALF(Ab, &As[0][0][0], 0, t2 * BK);
        PH_COMPUTE(0, 0, aS, b0);
        BAR;

        // ---- Ph6: quad(0-63, 32-63); stage A(t2)h1 ----
        DS_B4(b1, B1h, 32);
        STAGE_HALF(Ab, &As[0][1][0], 128, t2 * BK);
        PH_COMPUTE(0, 2, aS, b1);
        BAR;

        // ---- Ph7: quad(64-127, 0-31); stage B(t3)h0 (Bs[1][*] free) ----
        DS_A8(aT, A1, 64);
        STAGE_HALF(Bb, &Bs[1][0][0], 0, t3 * BK);
        PH_COMPUTE(4, 0, aT, b0);
        BAR;

        // ---- Ph8: quad(64-127, 32-63); stage B(t3)h1 + A(t3)h0; vmcnt(6) ----
        STAGE_HALF(Bb, &Bs[1][1][0], 128, t3 * BK);
        STAGE_HALF(Ab, &As[1][0][0], 0, t3 * BK);
        BAR; SB0;
        __builtin_amdgcn_s_setprio(1);
        MFMAQ(4, 2, aT, b1);
        __builtin_amdgcn_s_setprio(0);
        SB0;
        // Retires tile t2's 4 halves (Ph3,4,5,6); leaves Ph7,8a,8b in flight.
        asm volatile("s_waitcnt vmcnt(6)" ::: "memory");
        BAR;
    }
    asm volatile("s_waitcnt vmcnt(0)" ::: "memory");

    // Epilogue: C/D layout col = lane&15, row = (lane>>4)*4 + v (m89/m91).
    const int row0 = bm * BM + wm * 128 + (q << 2);
    const int col0 = bn * BN + wn * 64 + lr;
#pragma unroll
    for (int ni = 0; ni < 4; ++ni) {
        const int col = col0 + ni * 16;
        const float bv = bias[col];
#pragma unroll
        for (int mi = 0; mi < 8; ++mi) {
#pragma unroll
            for (int vv = 0; vv < 4; ++vv) {
                C[(size_t)(row0 + mi * 16 + vv) * N_DIM + col] = acc[mi][ni][vv] + bv;
            }
        }
    }
}

extern "C" void kernel_launch(void* const* d_in, const int* in_sizes, int n_in,
                              void* d_out, int out_size, void* d_ws, size_t ws_size,
                              hipStream_t stream) {
    const float* x    = (const float*)d_in[0];   // [4,2048,4096] f32
    const int*   wq   = (const int*)d_in[1];     // [11008,4096] int32 in 0..15
    const float* am   = (const float*)d_in[2];   // [11008,64] f32
    const float* bias = (const float*)d_in[3];   // [11008] f32
    float* out = (float*)d_out;                  // [4,2048,11008] f32

    const size_t w_elems = (size_t)N_DIM * K_DIM;
    const size_t x_elems = (size_t)M_DIM * K_DIM;
    const size_t need = (w_elems + x_elems) * sizeof(unsigned short);
    if (ws_size < need) return;

    unsigned short* wbf = (unsigned short*)d_ws;
    unsigned short* xbf = wbf + w_elems;

    nf4_dequant_w<<<(int)(w_elems / 8 / 256), 256, 0, stream>>>(wq, am, wbf);
    x_to_bf16<<<(int)(x_elems / 8 / 256), 256, 0, stream>>>(x, xbf);

    const int grid = (M_DIM / BM) * (N_DIM / BN);   // 32 * 43 = 1376
    gemm256<<<grid, 512, 0, stream>>>(xbf, wbf, bias, out);
}

// Round 12
// 828.403 us; speedup vs baseline: 1.2080x; 1.0403x over previous
//
#include <hip/hip_runtime.h>
#include <hip/hip_bf16.h>
#include <stdint.h>

typedef __attribute__((ext_vector_type(8))) short short8;
typedef __attribute__((ext_vector_type(8))) unsigned short ushort8;
typedef __attribute__((ext_vector_type(16))) float f32x16;

#define K_DIM 4096
#define N_DIM 11008
#define M_DIM 8192
#define BM 256
#define BN 256
#define BK 64
#define TILES (K_DIM / BK)   // 64

__constant__ float c_nf4[16] = {
    -1.0f, -0.6961928009986877f, -0.5250730514526367f, -0.39491748809814453f,
    -0.28444138169288635f, -0.18477343022823334f, -0.09105003625154495f, 0.0f,
    0.07958029955625534f, 0.16093020141124725f, 0.24611230194568634f,
    0.33791524171829224f, 0.44070982933044434f, 0.5626170039176941f,
    0.7229568362236023f, 1.0f};

__device__ __forceinline__ unsigned short f2bf(float f) {
    uint32_t u = __float_as_uint(f);
    u += 0x7fffu + ((u >> 16) & 1u);   // round-to-nearest-even (finite inputs)
    return (unsigned short)(u >> 16);
}

__global__ __launch_bounds__(256) void nf4_dequant_w(const int* __restrict__ q,
                                                     const float* __restrict__ absmax,
                                                     unsigned short* __restrict__ w) {
    __shared__ float lut[16];
    if (threadIdx.x < 16) lut[threadIdx.x] = c_nf4[threadIdx.x];
    __syncthreads();
    size_t t = (size_t)blockIdx.x * 256 + threadIdx.x;
    const int4* q4 = (const int4*)q;
    int4 qa = q4[2 * t];
    int4 qb = q4[2 * t + 1];
    float s = absmax[t >> 3];
    ushort8 o;
    o[0] = f2bf(lut[qa.x & 15] * s);
    o[1] = f2bf(lut[qa.y & 15] * s);
    o[2] = f2bf(lut[qa.z & 15] * s);
    o[3] = f2bf(lut[qa.w & 15] * s);
    o[4] = f2bf(lut[qb.x & 15] * s);
    o[5] = f2bf(lut[qb.y & 15] * s);
    o[6] = f2bf(lut[qb.z & 15] * s);
    o[7] = f2bf(lut[qb.w & 15] * s);
    ((ushort8*)w)[t] = o;
}

__global__ __launch_bounds__(256) void x_to_bf16(const float* __restrict__ x,
                                                 unsigned short* __restrict__ xb) {
    size_t t = (size_t)blockIdx.x * 256 + threadIdx.x;
    const float4* x4 = (const float4*)x;
    float4 a = x4[2 * t];
    float4 b = x4[2 * t + 1];
    ushort8 o;
    o[0] = f2bf(a.x); o[1] = f2bf(a.y); o[2] = f2bf(a.z); o[3] = f2bf(a.w);
    o[4] = f2bf(b.x); o[5] = f2bf(b.y); o[6] = f2bf(b.z); o[7] = f2bf(b.w);
    ((ushort8*)xb)[t] = o;
}

// Stage one 128-row half [128][64] (16 KB): 2 gloads/thread, LDS dest linear,
// GLOBAL source chunk G4-swizzled: LDS slot (r, s) holds global chunk s^(r&7).
#define STAGE_HALF(gbase, lds_half, row0, k0)                                 \
  do {                                                                        \
    _Pragma("unroll")                                                         \
    for (int _g = 0; _g < 2; ++_g) {                                          \
      const int _i = _g * 512 + tid;                                          \
      const int _r = _i >> 3;                                                 \
      const int _c = (_i & 7) ^ (_r & 7);                                     \
      __builtin_amdgcn_global_load_lds(                                       \
          (const __attribute__((address_space(1))) void*)((gbase) +           \
              (size_t)((row0) + _r) * K_DIM + (k0) + _c * 8),                 \
          (__attribute__((address_space(3))) void*)((lds_half) +              \
              (_g * 512 + wave * 64) * 8),                                    \
          16, 0, 0);                                                          \
    }                                                                         \
  } while (0)

// A-frag reads: dst[m][ks] for two 32-row m-blocks starting at MB0.
// addr = (mb*32 + lrow)*64 + swizzled-chunk(ks)  [elems].
#define DS_A2(dst, Ah, MB0)                                                   \
  do {                                                                        \
    _Pragma("unroll")                                                         \
    for (int _m = 0; _m < 2; ++_m) {                                          \
      const unsigned short* _p = (Ah) + ((MB0) + _m) * 2048 + arow;           \
      dst[_m][0] = *(const short8*)(_p + ck0);                                \
      dst[_m][1] = *(const short8*)(_p + ck1);                                \
      dst[_m][2] = *(const short8*)(_p + ck2);                                \
      dst[_m][3] = *(const short8*)(_p + ck3);                                \
    }                                                                         \
  } while (0)

// B-frag reads: dst[nb][ks] for the wave's two 32-col n-blocks.
#define DS_B2(dst, Bh)                                                        \
  do {                                                                        \
    _Pragma("unroll")                                                         \
    for (int _n = 0; _n < 2; ++_n) {                                          \
      const unsigned short* _p = (Bh) + (lb + _n * 32) * 64 + arow;           \
      dst[_n][0] = *(const short8*)(_p + ck0);                                \
      dst[_n][1] = *(const short8*)(_p + ck1);                                \
      dst[_n][2] = *(const short8*)(_p + ck2);                                \
      dst[_n][3] = *(const short8*)(_p + ck3);                                \
    }                                                                         \
  } while (0)

// 16 x mfma_f32_32x32x16_bf16: two m-blocks x two n-blocks x 4 k-steps.
// Order (ks, m, nb): same-acc dep distance 4 (~32 cy) > MFMA latency.
#define MFMAB(ACC0, Ar)                                                       \
  __builtin_amdgcn_s_setprio(1);                                              \
  do {                                                                        \
    _Pragma("unroll")                                                         \
    for (int _k = 0; _k < 4; ++_k) {                                          \
      _Pragma("unroll")                                                       \
      for (int _m = 0; _m < 2; ++_m) {                                        \
        _Pragma("unroll")                                                     \
        for (int _n = 0; _n < 2; ++_n)                                        \
          acc[(ACC0) + _m][_n] = __builtin_amdgcn_mfma_f32_32x32x16_bf16(     \
              Ar[_m][_k], bb[_n][_k], acc[(ACC0) + _m][_n], 0, 0, 0);         \
      }                                                                       \
    }                                                                         \
  } while (0);                                                                \
  __builtin_amdgcn_s_setprio(0);

// 256x256 tile, BK=64, 8 waves (2M x 4N, 128x64 each), dbuf-2, G4 swizzle,
// loose schedule (r7, best measured), 32x32x16 MFMA (2495 TF pipe, half the
// issue slots of 16x16x32 for the same FLOPs).
__global__ __launch_bounds__(512, 2) void gemm256(const unsigned short* __restrict__ A,
                                                  const unsigned short* __restrict__ B,
                                                  const float* __restrict__ bias,
                                                  float* __restrict__ C) {
    __shared__ unsigned short As[2][2][128 * 64];   // [buf][row-half], 64 KB
    __shared__ unsigned short Bs[2][2][128 * 64];   // 64 KB -> 128 KB total

    const int tid  = threadIdx.x;
    const int wave = tid >> 6;
    const int lane = tid & 63;
    const int wm = wave >> 2;               // 0..1 -> A row-half
    const int wn = wave & 3;                // 0..3 -> 64-col B slab
    const int lrow = lane & 31;             // frag row/col within 32-block
    const int khi  = lane >> 5;             // 0..1 -> k-half of frag
    const int lb   = (wn & 1) * 64;         // B row base within its half
    const int arow = lrow * 64;
    // Swizzled chunk offsets (elems) for k-steps 0..3:
    // chunk(ks) = ((ks<<1)|khi) ^ (lane&7); elem off = chunk*8.
    const int lx = lane & 7;
    const int ck0 = (((0 << 1) | khi) ^ lx) << 3;
    const int ck1 = (((1 << 1) | khi) ^ lx) << 3;
    const int ck2 = (((2 << 1) | khi) ^ lx) << 3;
    const int ck3 = (((3 << 1) | khi) ^ lx) << 3;

    // XCD-aware bijective swizzle: grid = 1376, 1376 % 8 == 0.
    const int nbn = N_DIM / BN;             // 43
    const int cpx = (int)gridDim.x >> 3;    // 172
    const int bid = (int)blockIdx.x;
    const int swz = (bid & 7) * cpx + (bid >> 3);
    const int bm = swz / nbn;
    const int bn = swz % nbn;

    const unsigned short* Ab = A + (size_t)bm * BM * K_DIM;
    const unsigned short* Bb = B + (size_t)bn * BN * K_DIM;

    f32x16 acc[4][2];
#pragma unroll
    for (int i = 0; i < 4; ++i)
#pragma unroll
        for (int j = 0; j < 2; ++j)
#pragma unroll
            for (int v = 0; v < 16; ++v) acc[i][j][v] = 0.0f;

    // Prologue: stage tile 0; drain; barrier.
    STAGE_HALF(Ab, &As[0][0][0], 0,   0); STAGE_HALF(Bb, &Bs[0][0][0], 0,   0);
    STAGE_HALF(Ab, &As[0][1][0], 128, 0); STAGE_HALF(Bb, &Bs[0][1][0], 128, 0);
    asm volatile("s_waitcnt vmcnt(0)" ::: "memory");
    asm volatile("s_barrier" ::: "memory");

    short8 aE[2][4], aO[2][4], bb[2][4];

#pragma unroll 1
    for (int t = 0; t < TILES; ++t) {
        const int p = t & 1;
        int t1 = t + 1; if (t1 >= TILES) t1 = 0;   // tail wrap: harmless
        const int k1 = t1 * BK;
        const unsigned short* Ah = &As[p][wm][0];
        const unsigned short* Bh = &Bs[p][wn >> 1][0];

        // Front-loaded reads for burst 1 (16 x ds_read_b128).
        DS_B2(bb, Bh);          // B both n-blocks, all k-steps
        DS_A2(aE, Ah, 0);       // A m-blocks 0,1

        // Stage tile t+1 (8 gloads; land by tile end).
        STAGE_HALF(Ab, &As[p ^ 1][0][0], 0,   k1);
        STAGE_HALF(Bb, &Bs[p ^ 1][0][0], 0,   k1);
        STAGE_HALF(Ab, &As[p ^ 1][1][0], 128, k1);
        STAGE_HALF(Bb, &Bs[p ^ 1][1][0], 128, k1);

        MFMAB(0, aE);           // burst 1: m-blocks 0,1

        DS_A2(aO, Ah, 2);       // A m-blocks 2,3 stream in burst-1 shadow

        MFMAB(2, aO);           // burst 2: m-blocks 2,3

        // Tile boundary: reads done (WAR), next tile landed (RAW), 1 barrier.
        asm volatile("s_waitcnt lgkmcnt(0)" ::: "memory");
        __builtin_amdgcn_sched_barrier(0);
        asm volatile("s_waitcnt vmcnt(0)" ::: "memory");
        asm volatile("s_barrier" ::: "memory");
    }
    asm volatile("s_waitcnt vmcnt(0)" ::: "memory");

    // Epilogue. 32x32 C/D layout (m74/m101): col = lane&31,
    // row = (reg&3) + 8*(reg>>2) + 4*(lane>>5).
    const int rbase = bm * BM + wm * 128 + 4 * khi;
    const int col0 = bn * BN + wn * 64 + lrow;
#pragma unroll
    for (int nb = 0; nb < 2; ++nb) {
        const int col = col0 + nb * 32;
        const float bv = bias[col];
#pragma unroll
        for (int mb = 0; mb < 4; ++mb) {
#pragma unroll
            for (int r = 0; r < 16; ++r) {
                const int row = rbase + mb * 32 + (r & 3) + 8 * (r >> 2);
                C[(size_t)row * N_DIM + col] = acc[mb][nb][r] + bv;
            }
        }
    }
}

extern "C" void kernel_launch(void* const* d_in, const int* in_sizes, int n_in,
                              void* d_out, int out_size, void* d_ws, size_t ws_size,
                              hipStream_t stream) {
    const float* x    = (const float*)d_in[0];   // [4,2048,4096] f32
    const int*   wq   = (const int*)d_in[1];     // [11008,4096] int32 in 0..15
    const float* am   = (const float*)d_in[2];   // [11008,64] f32
    const float* bias = (const float*)d_in[3];   // [11008] f32
    float* out = (float*)d_out;                  // [4,2048,11008] f32

    const size_t w_elems = (size_t)N_DIM * K_DIM;
    const size_t x_elems = (size_t)M_DIM * K_DIM;
    const size_t need = (w_elems + x_elems) * sizeof(unsigned short);
    if (ws_size < need) return;

    unsigned short* wbf = (unsigned short*)d_ws;
    unsigned short* xbf = wbf + w_elems;

    nf4_dequant_w<<<(int)(w_elems / 8 / 256), 256, 0, stream>>>(wq, am, wbf);
    x_to_bf16<<<(int)(x_elems / 8 / 256), 256, 0, stream>>>(x, xbf);

    const int grid = (M_DIM / BM) * (N_DIM / BN);   // 32 * 43 = 1376
    gemm256<<<grid, 512, 0, stream>>>(xbf, wbf, bias, out);
}

// Round 13
// 816.181 us; speedup vs baseline: 1.2261x; 1.0150x over previous
//
#include <hip/hip_runtime.h>
#include <hip/hip_bf16.h>
#include <stdint.h>

typedef __attribute__((ext_vector_type(8))) short short8;
typedef __attribute__((ext_vector_type(8))) unsigned short ushort8;
typedef __attribute__((ext_vector_type(4))) float f32x4;

#define K_DIM 4096
#define N_DIM 11008
#define M_DIM 8192
#define BM 256
#define BN 256
#define BK 64
#define TILES (K_DIM / BK)   // 64

#define W_ELEMS ((size_t)N_DIM * K_DIM)      // 45,088,768
#define X_ELEMS ((size_t)M_DIM * K_DIM)      // 33,554,432
#define NDQ ((int)(W_ELEMS / 8 / 256))       // 22016 dequant blocks
#define NCV ((int)(X_ELEMS / 8 / 256))       // 16384 convert blocks

__constant__ float c_nf4[16] = {
    -1.0f, -0.6961928009986877f, -0.5250730514526367f, -0.39491748809814453f,
    -0.28444138169288635f, -0.18477343022823334f, -0.09105003625154495f, 0.0f,
    0.07958029955625534f, 0.16093020141124725f, 0.24611230194568634f,
    0.33791524171829224f, 0.44070982933044434f, 0.5626170039176941f,
    0.7229568362236023f, 1.0f};

__device__ __forceinline__ unsigned short f2bf(float f) {
    uint32_t u = __float_as_uint(f);
    u += 0x7fffu + ((u >> 16) & 1u);   // round-to-nearest-even (finite inputs)
    return (unsigned short)(u >> 16);
}

// Fused pre-pass: blocks [0, NDQ) dequant W (int32 NF4 -> bf16);
// blocks [NDQ, NDQ+NCV) convert x (f32 -> bf16). Same per-thread code as the
// r7-measured separate kernels; fusion saves a launch and lets convert
// backfill the dequant tail.
__global__ __launch_bounds__(256) void prepass(const int* __restrict__ q,
                                               const float* __restrict__ absmax,
                                               unsigned short* __restrict__ w,
                                               const float* __restrict__ x,
                                               unsigned short* __restrict__ xb) {
    __shared__ float lut[16];
    if (threadIdx.x < 16) lut[threadIdx.x] = c_nf4[threadIdx.x];
    __syncthreads();
    if (blockIdx.x < NDQ) {
        size_t t = (size_t)blockIdx.x * 256 + threadIdx.x;
        const int4* q4 = (const int4*)q;
        int4 qa = q4[2 * t];
        int4 qb = q4[2 * t + 1];
        float s = absmax[t >> 3];
        ushort8 o;
        o[0] = f2bf(lut[qa.x & 15] * s);
        o[1] = f2bf(lut[qa.y & 15] * s);
        o[2] = f2bf(lut[qa.z & 15] * s);
        o[3] = f2bf(lut[qa.w & 15] * s);
        o[4] = f2bf(lut[qb.x & 15] * s);
        o[5] = f2bf(lut[qb.y & 15] * s);
        o[6] = f2bf(lut[qb.z & 15] * s);
        o[7] = f2bf(lut[qb.w & 15] * s);
        ((ushort8*)w)[t] = o;
    } else {
        size_t t = (size_t)(blockIdx.x - NDQ) * 256 + threadIdx.x;
        const float4* x4 = (const float4*)x;
        float4 a = x4[2 * t];
        float4 b = x4[2 * t + 1];
        ushort8 o;
        o[0] = f2bf(a.x); o[1] = f2bf(a.y); o[2] = f2bf(a.z); o[3] = f2bf(a.w);
        o[4] = f2bf(b.x); o[5] = f2bf(b.y); o[6] = f2bf(b.z); o[7] = f2bf(b.w);
        ((ushort8*)xb)[t] = o;
    }
}

// Stage one 128-row half [128][64] (16 KB): 2 gloads/thread, LDS dest linear,
// GLOBAL source chunk G4-swizzled (r4/r6/r7-proven zero-conflict):
// LDS slot (r, s) holds global chunk s ^ (r&7).
#define STAGE_HALF(gbase, lds_half, row0, k0)                                 \
  do {                                                                        \
    _Pragma("unroll")                                                         \
    for (int _g = 0; _g < 2; ++_g) {                                          \
      const int _i = _g * 512 + tid;       /* slot 0..1023 */                 \
      const int _r = _i >> 3;              /* local row 0..127 */             \
      const int _c = (_i & 7) ^ (_r & 7);  /* global chunk */                 \
      __builtin_amdgcn_global_load_lds(                                       \
          (const __attribute__((address_space(1))) void*)((gbase) +           \
              (size_t)((row0) + _r) * K_DIM + (k0) + _c * 8),                 \
          (__attribute__((address_space(3))) void*)((lds_half) +              \
              (_g * 512 + wave * 64) * 8),                                    \
          16, 0, 0);                                                          \
    }                                                                         \
  } while (0)

// Frag reads from a [128][64] half into a NAMED register set (rule 20).
#define DS_A4(dst, rbase, X)                                                  \
  dst[0] = *(const short8*)(Ah + ((rbase) +  0) * 64 + (roff ^ (X)));         \
  dst[1] = *(const short8*)(Ah + ((rbase) + 16) * 64 + (roff ^ (X)));         \
  dst[2] = *(const short8*)(Ah + ((rbase) + 32) * 64 + (roff ^ (X)));         \
  dst[3] = *(const short8*)(Ah + ((rbase) + 48) * 64 + (roff ^ (X)));

#define DS_B4(dst, X)                                                         \
  dst[0] = *(const short8*)(Bh + (bbase +  0) * 64 + (roff ^ (X)));           \
  dst[1] = *(const short8*)(Bh + (bbase + 16) * 64 + (roff ^ (X)));           \
  dst[2] = *(const short8*)(Bh + (bbase + 32) * 64 + (roff ^ (X)));           \
  dst[3] = *(const short8*)(Bh + (bbase + 48) * 64 + (roff ^ (X)));

#define MFMA16(MI0, Ar, Br)                                                   \
  __builtin_amdgcn_s_setprio(1);                                              \
  do {                                                                        \
    _Pragma("unroll")                                                         \
    for (int _m = 0; _m < 4; ++_m) {                                          \
      _Pragma("unroll")                                                       \
      for (int _n = 0; _n < 4; ++_n)                                          \
        acc[(MI0) + _m][_n] = __builtin_amdgcn_mfma_f32_16x16x32_bf16(        \
            Ar[_m], Br[_n], acc[(MI0) + _m][_n], 0, 0, 0);                    \
    }                                                                         \
  } while (0);                                                                \
  __builtin_amdgcn_s_setprio(0);

// r7 (measured best: 788-798 us GEMM): 256x256 tile, BK=64, 8 waves (2M x 4N),
// dbuf-2, G4 swizzle, loose group (1 barrier/tile), register-pipelined
// operands (dedicated sets -> ds_reads stream inside the MFMA shadow).
__global__ __launch_bounds__(512, 2) void gemm256(const unsigned short* __restrict__ A,
                                                  const unsigned short* __restrict__ B,
                                                  const float* __restrict__ bias,
                                                  float* __restrict__ C) {
    __shared__ unsigned short As[2][2][128 * 64];   // [buf][row-half], 64 KB
    __shared__ unsigned short Bs[2][2][128 * 64];   // 64 KB -> 128 KB total

    const int tid  = threadIdx.x;
    const int wave = tid >> 6;
    const int lane = tid & 63;
    const int wm = wave >> 2;               // 0..1 -> A row-half
    const int wn = wave & 3;                // 0..3 -> 64-row B slab
    const int lr = lane & 15;
    const int q  = lane >> 4;               // 0..3
    // Zero-conflict swizzled read offset (elements), kk=0; kk=32 -> roff^32.
    const int roff = lr * 64 + ((q ^ (lr & 7)) << 3);
    const int bbase = (wn & 1) * 64;        // B row base within its half

    // XCD-aware bijective swizzle: grid = 1376, 1376 % 8 == 0.
    const int nbn = N_DIM / BN;             // 43
    const int cpx = (int)gridDim.x >> 3;    // 172
    const int bid = (int)blockIdx.x;
    const int swz = (bid & 7) * cpx + (bid >> 3);
    const int bm = swz / nbn;
    const int bn = swz % nbn;

    const unsigned short* Ab = A + (size_t)bm * BM * K_DIM;
    const unsigned short* Bb = B + (size_t)bn * BN * K_DIM;

    f32x4 acc[8][4];
#pragma unroll
    for (int i = 0; i < 8; ++i)
#pragma unroll
        for (int j = 0; j < 4; ++j)
#pragma unroll
            for (int v = 0; v < 4; ++v) acc[i][j][v] = 0.0f;

    // Prologue: stage tile 0 (4 halves, 8 loads/thread); drain; barrier.
    STAGE_HALF(Ab, &As[0][0][0], 0,   0); STAGE_HALF(Bb, &Bs[0][0][0], 0,   0);
    STAGE_HALF(Ab, &As[0][1][0], 128, 0); STAGE_HALF(Bb, &Bs[0][1][0], 128, 0);
    asm volatile("s_waitcnt vmcnt(0)" ::: "memory");
    asm volatile("s_barrier" ::: "memory");

    // Dedicated operand register sets (liveness-disjoint across clusters).
    short8 aA[4], aB[4], aC[4], aD[4], bE[4], bO[4];

#pragma unroll 1
    for (int t = 0; t < TILES; ++t) {
        const int p = t & 1;
        int t1 = t + 1; if (t1 >= TILES) t1 = 0;   // tail wrap: harmless
        const int k1 = t1 * BK;
        const unsigned short* Ah = &As[p][wm][0];
        const unsigned short* Bh = &Bs[p][wn >> 1][0];

        // Front-loaded reads for clusters 0 and 1 (12 x ds_read_b128).
        DS_A4(aA, 0, 0);        // A rows 0..63,  kk=0
        DS_B4(bE, 0);           // B kk=0 (shared by clusters 0,1)
        DS_A4(aB, 64, 0);       // A rows 64..127, kk=0

        // Stage tile t+1 into the other buffer (8 gloads, land by tile end).
        STAGE_HALF(Ab, &As[p ^ 1][0][0], 0,   k1);
        STAGE_HALF(Bb, &Bs[p ^ 1][0][0], 0,   k1);
        STAGE_HALF(Ab, &As[p ^ 1][1][0], 128, k1);
        STAGE_HALF(Bb, &Bs[p ^ 1][1][0], 128, k1);

        MFMA16(0, aA, bE);      // cluster 0

        // These stream in cluster-0/1's shadow (dedicated regs, no WAR).
        DS_B4(bO, 32);          // B kk=32
        DS_A4(aC, 0, 32);       // A rows 0..63,  kk=32

        MFMA16(4, aB, bE);      // cluster 1

        DS_A4(aD, 64, 32);      // A rows 64..127, kk=32

        MFMA16(0, aC, bO);      // cluster 2
        MFMA16(4, aD, bO);      // cluster 3

        // Group boundary: pin read completion (rule 18), then free drain
        // (vmcnt(0) waits on loads issued a full tile ago) + barrier.
        asm volatile("s_waitcnt lgkmcnt(0)" ::: "memory");
        __builtin_amdgcn_sched_barrier(0);
        asm volatile("s_waitcnt vmcnt(0)" ::: "memory");
        asm volatile("s_barrier" ::: "memory");
    }

    // Epilogue: C/D layout col = lane&15, row = (lane>>4)*4 + v (m89/m91).
    const int row0 = bm * BM + wm * 128 + (q << 2);
    const int col0 = bn * BN + wn * 64 + lr;
#pragma unroll
    for (int ni = 0; ni < 4; ++ni) {
        const int col = col0 + ni * 16;
        const float bv = bias[col];
#pragma unroll
        for (int mi = 0; mi < 8; ++mi) {
#pragma unroll
            for (int v = 0; v < 4; ++v) {
                C[(size_t)(row0 + mi * 16 + v) * N_DIM + col] = acc[mi][ni][v] + bv;
            }
        }
    }
}

extern "C" void kernel_launch(void* const* d_in, const int* in_sizes, int n_in,
                              void* d_out, int out_size, void* d_ws, size_t ws_size,
                              hipStream_t stream) {
    const float* x    = (const float*)d_in[0];   // [4,2048,4096] f32
    const int*   wq   = (const int*)d_in[1];     // [11008,4096] int32 in 0..15
    const float* am   = (const float*)d_in[2];   // [11008,64] f32
    const float* bias = (const float*)d_in[3];   // [11008] f32
    float* out = (float*)d_out;                  // [4,2048,11008] f32

    const size_t need = (W_ELEMS + X_ELEMS) * sizeof(unsigned short);
    if (ws_size < need) return;

    unsigned short* wbf = (unsigned short*)d_ws;
    unsigned short* xbf = wbf + W_ELEMS;

    prepass<<<NDQ + NCV, 256, 0, stream>>>(wq, am, wbf, x, xbf);

    const int grid = (M_DIM / BM) * (N_DIM / BN);   // 32 * 43 = 1376
    gemm256<<<grid, 512, 0, stream>>>(xbf, wbf, bias, out);
}